// Round 3
// baseline (161.687 us; speedup 1.0000x reference)
//
#include <hip/hip_runtime.h>

// Closed-form: all 10 segment steps are exp(-i*phi_s*H) with the SAME
// traceless Hermitian 2x2 H, so the product is exp(-i*(sum phi)*H).
// infidelity_b = 1 - (cr * sin(DT*S_b*r) / r)^2,  S_b = sum_s omega[b,s]
// loss = mean((infid_data - infidelity)^2)
//
// R2 -> R3: R2 (1024-row block tile, 45.5KB LDS, block-wide barrier) ran
// 60us with every pipe idle: 3 blocks/CU + full vmcnt(0) drain at the
// barrier serialized everything. Now each WAVE stages its own 128 rows
// (10 coalesced float2 loads/lane) into a private 5.5KB LDS region;
// block LDS = 22.5KB -> 7 blocks/CU (28 waves), grid 3907. LDS rows
// padded to 11 floats: compute reads at lane stride 11 (coprime w/ 32)
// = 2-way = free. All hot-loop index math is 32-bit.

#define ND 2000000
#define NS 10
#define RPW 128                    // rows per wave
#define WPB 4                      // waves per block
#define RPB (RPW * WPB)            // 512 rows per block
#define PAD 11                     // LDS floats per row
#define WTILE (RPW * PAD)          // 1408 floats per wave tile (mult of 32)

__global__ __launch_bounds__(256) void loss_kernel(
    const float* __restrict__ para,
    const float* __restrict__ omega,
    const float* __restrict__ infid,
    float* __restrict__ out) {

    __shared__ float lds[WPB * WTILE];   // 22528 B -> 7 blocks/CU

    // Scalar precompute (broadcast loads, cached)
    const float x00 = para[0], x01 = para[1], x10 = para[2], x11 = para[3];
    const float a  = 0.5f * (x00 - x11);
    const float cr = 0.5f + 0.5f * (x01 + x10);
    const float ci = 0.5f * (x01 - x10);
    const float r  = sqrtf(a * a + cr * cr + ci * ci);
    const float cr_over_r = cr / r;
    const float dt_r = 0.1f * r;         // DT * r

    const int tid  = threadIdx.x;
    const int lane = tid & 63;
    const int w    = tid >> 6;
    const unsigned rowW = (unsigned)blockIdx.x * RPB + (unsigned)w * RPW;
    const unsigned f2W  = rowW * 5u;     // first float2 of this wave's tile
    float* wtile = &lds[w * WTILE];

    // ---- Stage 128 rows = 320 float2 per wave, fully coalesced ----
    const float2* om2 = (const float2*)omega;
    #pragma unroll
    for (int k = 0; k < 10; ++k) {
        const unsigned fl  = 64u * k + (unsigned)lane;  // local float2 idx
        const unsigned idx = f2W + fl;
        float2 v = make_float2(0.0f, 0.0f);
        if (idx < (unsigned)(ND * 5)) v = om2[idx];     // 8B-aligned, coalesced
        const unsigned rl = fl / 5u;                    // local row
        const unsigned p  = fl % 5u;                    // float2 pos in row
        const unsigned o  = rl * PAD + p * 2u;
        wtile[o]     = v.x;
        wtile[o + 1] = v.y;
    }
    __syncthreads();

    // ---- Per-row compute: 2 rows per lane at stride-11 (2-way, free) ----
    float acc = 0.0f;
    #pragma unroll
    for (int q = 0; q < 2; ++q) {
        const unsigned rl  = (unsigned)lane + 64u * q;
        const unsigned row = rowW + rl;
        if (row < (unsigned)ND) {
            const float* rp = &wtile[rl * PAD];
            float s = 0.0f;
            #pragma unroll
            for (int j = 0; j < 10; ++j) s += rp[j];
            const float theta = dt_r * s;
            const float t = cr_over_r * sinf(theta);
            const float inf_calc = 1.0f - t * t;
            const float d = infid[row] - inf_calc;      // coalesced
            acc += d * d;
        }
    }

    // ---- wave (64-lane) shuffle reduction ----
    #pragma unroll
    for (int off = 32; off > 0; off >>= 1)
        acc += __shfl_down(acc, off, 64);

    __shared__ float wsum[WPB];
    if (lane == 0) wsum[w] = acc;
    __syncthreads();
    if (tid == 0) {
        const float t = wsum[0] + wsum[1] + wsum[2] + wsum[3];
        // out starts at 0xAAAAAAAA = -3.03e-13f: negligible, deterministic;
        // skipping the memset saves a graph dispatch.
        atomicAdd(out, t * (1.0f / (float)ND));
    }
}

extern "C" void kernel_launch(void* const* d_in, const int* in_sizes, int n_in,
                              void* d_out, int out_size, void* d_ws, size_t ws_size,
                              hipStream_t stream) {
    const float* para  = (const float*)d_in[0];   // (2,2)
    const float* omega = (const float*)d_in[1];   // (2M, 10)
    const float* infid = (const float*)d_in[2];   // (2M,)
    float* out = (float*)d_out;

    const int grid = (ND + RPB - 1) / RPB;        // 3907
    loss_kernel<<<grid, 256, 0, stream>>>(para, omega, infid, out);
}

// Round 4
// 133.554 us; speedup vs baseline: 1.2106x; 1.2106x over previous
//
#include <hip/hip_runtime.h>

// Closed-form: all 10 segment steps are exp(-i*phi_s*H) with the SAME
// traceless Hermitian 2x2 H, so the product is exp(-i*(sum phi)*H).
// infidelity_b = 1 - (cr * sin(DT*S_b*r) / r)^2,  S_b = sum_s omega[b,s]
// loss = mean((infid_data - infidelity)^2)
//
// R3 -> R4: warm-L3 replays of R3 still took 67us with FETCH~0 -> the
// kernel was NOT memory-bound. Culprit: 3907 blocks all atomicAdd-ing
// the SAME address; same-line atomics serialize across the 8 XCDs
// (~12ns each -> ~49us serialized tail, matching 67us = 49 + ~18us
// work). Now each block stores its partial to a distinct d_ws slot
// (no contention) and a tiny second kernel reduces the 3907 partials
// and writes out[0] with a plain store.

#define ND 2000000
#define NS 10
#define RPW 128                    // rows per wave
#define WPB 4                      // waves per block
#define RPB (RPW * WPB)            // 512 rows per block
#define PAD 11                     // LDS floats per row (coprime w/ 32 banks)
#define WTILE (RPW * PAD)          // 1408 floats per wave tile
#define GRID ((ND + RPB - 1) / RPB)  // 3907 blocks

__global__ __launch_bounds__(256) void loss_kernel(
    const float* __restrict__ para,
    const float* __restrict__ omega,
    const float* __restrict__ infid,
    float* __restrict__ partial) {

    __shared__ float lds[WPB * WTILE];   // 22528 B -> 7 blocks/CU

    // Scalar precompute (broadcast loads, cached)
    const float x00 = para[0], x01 = para[1], x10 = para[2], x11 = para[3];
    const float a  = 0.5f * (x00 - x11);
    const float cr = 0.5f + 0.5f * (x01 + x10);
    const float ci = 0.5f * (x01 - x10);
    const float r  = sqrtf(a * a + cr * cr + ci * ci);
    const float cr_over_r = cr / r;
    const float dt_r = 0.1f * r;         // DT * r

    const int tid  = threadIdx.x;
    const int lane = tid & 63;
    const int w    = tid >> 6;
    const unsigned rowW = (unsigned)blockIdx.x * RPB + (unsigned)w * RPW;
    const unsigned f2W  = rowW * 5u;     // first float2 of this wave's tile
    float* wtile = &lds[w * WTILE];

    // ---- Stage 128 rows = 320 float2 per wave, fully coalesced ----
    const float2* om2 = (const float2*)omega;
    #pragma unroll
    for (int k = 0; k < 10; ++k) {
        const unsigned fl  = 64u * k + (unsigned)lane;  // local float2 idx
        const unsigned idx = f2W + fl;
        float2 v = make_float2(0.0f, 0.0f);
        if (idx < (unsigned)(ND * 5)) v = om2[idx];     // 8B-aligned, coalesced
        const unsigned rl = fl / 5u;                    // local row
        const unsigned p  = fl % 5u;                    // float2 pos in row
        const unsigned o  = rl * PAD + p * 2u;
        wtile[o]     = v.x;
        wtile[o + 1] = v.y;
    }
    __syncthreads();

    // ---- Per-row compute: 2 rows per lane at stride-11 (2-way, free) ----
    float acc = 0.0f;
    #pragma unroll
    for (int q = 0; q < 2; ++q) {
        const unsigned rl  = (unsigned)lane + 64u * q;
        const unsigned row = rowW + rl;
        if (row < (unsigned)ND) {
            const float* rp = &wtile[rl * PAD];
            float s = 0.0f;
            #pragma unroll
            for (int j = 0; j < 10; ++j) s += rp[j];
            const float theta = dt_r * s;
            const float t = cr_over_r * sinf(theta);
            const float inf_calc = 1.0f - t * t;
            const float d = infid[row] - inf_calc;      // coalesced
            acc += d * d;
        }
    }

    // ---- wave (64-lane) shuffle reduction ----
    #pragma unroll
    for (int off = 32; off > 0; off >>= 1)
        acc += __shfl_down(acc, off, 64);

    __shared__ float wsum[WPB];
    if (lane == 0) wsum[w] = acc;
    __syncthreads();
    if (tid == 0) {
        // distinct slot per block: NO same-address atomic contention
        partial[blockIdx.x] = wsum[0] + wsum[1] + wsum[2] + wsum[3];
    }
}

__global__ __launch_bounds__(256) void reduce_kernel(
    const float* __restrict__ partial,
    float* __restrict__ out) {

    const int tid = threadIdx.x;
    float acc = 0.0f;
    for (int i = tid; i < GRID; i += 256) acc += partial[i];

    #pragma unroll
    for (int off = 32; off > 0; off >>= 1)
        acc += __shfl_down(acc, off, 64);

    __shared__ float wsum[4];
    const int lane = tid & 63;
    const int w    = tid >> 6;
    if (lane == 0) wsum[w] = acc;
    __syncthreads();
    if (tid == 0)
        out[0] = (wsum[0] + wsum[1] + wsum[2] + wsum[3]) * (1.0f / (float)ND);
}

extern "C" void kernel_launch(void* const* d_in, const int* in_sizes, int n_in,
                              void* d_out, int out_size, void* d_ws, size_t ws_size,
                              hipStream_t stream) {
    const float* para  = (const float*)d_in[0];   // (2,2)
    const float* omega = (const float*)d_in[1];   // (2M, 10)
    const float* infid = (const float*)d_in[2];   // (2M,)
    float* out     = (float*)d_out;
    float* partial = (float*)d_ws;                // 3907 * 4 B = 15.6 KB

    loss_kernel<<<GRID, 256, 0, stream>>>(para, omega, infid, partial);
    reduce_kernel<<<1, 256, 0, stream>>>(partial, out);
}

// Round 5
// 124.887 us; speedup vs baseline: 1.2947x; 1.0694x over previous
//
#include <hip/hip_runtime.h>

// Closed-form: all 10 segment steps are exp(-i*phi_s*H) with the SAME
// traceless Hermitian 2x2 H, so the product is exp(-i*(sum phi)*H).
// infidelity_b = 1 - (cr * sin(DT*S_b*r) / r)^2,  S_b = sum_s omega[b,s]
// loss = mean((infid_data - infidelity)^2)
//
// R4 -> R5: accounting across rounds shows the LDS-staged kernel was
// ~35us while R1's direct-load work was ~20us -- the LDS round-trip +
// barrier + div/mod addressing cost more than it saved. Line-lookup
// math: only R1's 160B/lane stride (64 lines/instr, ~2.5 TB/s cap) was
// pathological; at 80B/lane a float4 instr spans 40 lines (~26 TB/s
// cap >> HBM 6.3). So: direct loads, 2 rows/thread = 5x float4
// (16B-aligned since tid*80 % 16 == 0), no LDS tile, no barrier,
// per-block partial to a distinct d_ws slot, tiny reduce kernel.

#define ND 2000000
#define BLK 256
#define RPB (2 * BLK)                       // 512 rows per block
#define GRID ((ND + RPB - 1) / RPB)         // 3907

__global__ __launch_bounds__(256) void loss_kernel(
    const float* __restrict__ para,
    const float* __restrict__ omega,
    const float* __restrict__ infid,
    float* __restrict__ partial) {

    // Scalar precompute (broadcast loads, cached)
    const float x00 = para[0], x01 = para[1], x10 = para[2], x11 = para[3];
    const float a  = 0.5f * (x00 - x11);
    const float cr = 0.5f + 0.5f * (x01 + x10);
    const float ci = 0.5f * (x01 - x10);
    const float r  = sqrtf(a * a + cr * cr + ci * ci);
    const float cr_over_r = cr / r;
    const float dt_r = 0.1f * r;            // DT * r

    const unsigned tid  = (unsigned)blockIdx.x * BLK + threadIdx.x;
    const unsigned row0 = tid * 2u;         // 2 consecutive rows per thread
    float acc = 0.0f;

    if (row0 < (unsigned)ND) {              // ND even -> both rows valid
        // 20 floats = 5 x float4, base = tid*80 B (16B-aligned)
        const float4* p4 = (const float4*)omega + tid * 5u;
        const float4 v0 = p4[0];
        const float4 v1 = p4[1];
        const float4 v2 = p4[2];
        const float4 v3 = p4[3];
        const float4 v4 = p4[4];

        const float s0 = ((v0.x + v0.y) + (v0.z + v0.w))
                       + ((v1.x + v1.y) + (v1.z + v1.w)) + (v2.x + v2.y);
        const float s1 = ((v2.z + v2.w) + (v3.x + v3.y))
                       + ((v3.z + v3.w) + (v4.x + v4.y)) + (v4.z + v4.w);

        const float2 fi = *((const float2*)infid + tid);   // coalesced, 8B

        const float t0 = cr_over_r * sinf(dt_r * s0);
        const float t1 = cr_over_r * sinf(dt_r * s1);
        const float d0 = fi.x - (1.0f - t0 * t0);
        const float d1 = fi.y - (1.0f - t1 * t1);
        acc = d0 * d0 + d1 * d1;
    }

    // wave (64-lane) shuffle reduction
    #pragma unroll
    for (int off = 32; off > 0; off >>= 1)
        acc += __shfl_down(acc, off, 64);

    __shared__ float wsum[4];               // 256 threads = 4 waves
    const int lane = threadIdx.x & 63;
    const int w    = threadIdx.x >> 6;
    if (lane == 0) wsum[w] = acc;
    __syncthreads();
    if (threadIdx.x == 0) {
        // distinct slot per block: no same-address atomic contention
        partial[blockIdx.x] = (wsum[0] + wsum[1]) + (wsum[2] + wsum[3]);
    }
}

__global__ __launch_bounds__(256) void reduce_kernel(
    const float* __restrict__ partial,
    float* __restrict__ out) {

    const int tid = threadIdx.x;
    float acc = 0.0f;
    for (int i = tid; i < GRID; i += 256) acc += partial[i];

    #pragma unroll
    for (int off = 32; off > 0; off >>= 1)
        acc += __shfl_down(acc, off, 64);

    __shared__ float wsum[4];
    const int lane = tid & 63;
    const int w    = tid >> 6;
    if (lane == 0) wsum[w] = acc;
    __syncthreads();
    if (tid == 0)
        out[0] = ((wsum[0] + wsum[1]) + (wsum[2] + wsum[3])) * (1.0f / (float)ND);
}

extern "C" void kernel_launch(void* const* d_in, const int* in_sizes, int n_in,
                              void* d_out, int out_size, void* d_ws, size_t ws_size,
                              hipStream_t stream) {
    const float* para  = (const float*)d_in[0];   // (2,2)
    const float* omega = (const float*)d_in[1];   // (2M, 10)
    const float* infid = (const float*)d_in[2];   // (2M,)
    float* out     = (float*)d_out;
    float* partial = (float*)d_ws;                // 3907 * 4 B = 15.6 KB

    loss_kernel<<<GRID, BLK, 0, stream>>>(para, omega, infid, partial);
    reduce_kernel<<<1, 256, 0, stream>>>(partial, out);
}

// Round 6
// 120.383 us; speedup vs baseline: 1.3431x; 1.0374x over previous
//
#include <hip/hip_runtime.h>

// Closed-form: all 10 segment steps are exp(-i*phi_s*H) with the SAME
// traceless Hermitian 2x2 H, so the product is exp(-i*(sum phi)*H).
// infidelity_b = 1 - (cr * sin(DT*S_b*r) / r)^2,  S_b = sum_s omega[b,s]
// loss = mean((infid_data - infidelity)^2)
//
// R5 -> R6: loss_kernel was still ~24us vs a ~10-14us floor (L3 absorbs
// ~half the 88MB: FETCH was 43MB in R2/R3). Suspect: block churn + low
// per-wave MLP -- 3907 short blocks, each lane with only 80B in flight.
// Now 1024 persistent-ish blocks; each thread grid-strides 4 tiles
// (8 rows, 20 float4 loads hoistable -> 320B/lane in flight), partials
// shrink to 1024. Same contention-free two-kernel reduction.

#define ND 2000000
#define BLK 256
#define NBLOCKS 1024
#define NTHREADS (NBLOCKS * BLK)            // 262,144
#define NTILES (ND / 2)                     // 1,000,000 (2 rows per tile)
#define NITER 4                             // ceil(NTILES / NTHREADS)

__global__ __launch_bounds__(256) void loss_kernel(
    const float* __restrict__ para,
    const float* __restrict__ omega,
    const float* __restrict__ infid,
    float* __restrict__ partial) {

    // Scalar precompute (broadcast loads, cached)
    const float x00 = para[0], x01 = para[1], x10 = para[2], x11 = para[3];
    const float a  = 0.5f * (x00 - x11);
    const float cr = 0.5f + 0.5f * (x01 + x10);
    const float ci = 0.5f * (x01 - x10);
    const float r  = sqrtf(a * a + cr * cr + ci * ci);
    const float cr_over_r = cr / r;
    const float dt_r = 0.1f * r;            // DT * r

    const unsigned tid0 = (unsigned)blockIdx.x * BLK + threadIdx.x;
    float acc = 0.0f;

    #pragma unroll
    for (int it = 0; it < NITER; ++it) {
        const unsigned t = tid0 + (unsigned)it * NTHREADS;  // tile index
        if (t < (unsigned)NTILES) {
            // 2 rows = 20 floats = 5 x float4, base = t*80 B (16B-aligned)
            const float4* p4 = (const float4*)omega + t * 5u;
            const float4 v0 = p4[0];
            const float4 v1 = p4[1];
            const float4 v2 = p4[2];
            const float4 v3 = p4[3];
            const float4 v4 = p4[4];

            const float s0 = ((v0.x + v0.y) + (v0.z + v0.w))
                           + ((v1.x + v1.y) + (v1.z + v1.w)) + (v2.x + v2.y);
            const float s1 = ((v2.z + v2.w) + (v3.x + v3.y))
                           + ((v3.z + v3.w) + (v4.x + v4.y)) + (v4.z + v4.w);

            const float2 fi = *((const float2*)infid + t);  // coalesced, 8B

            const float t0 = cr_over_r * sinf(dt_r * s0);
            const float t1 = cr_over_r * sinf(dt_r * s1);
            const float d0 = fi.x - (1.0f - t0 * t0);
            const float d1 = fi.y - (1.0f - t1 * t1);
            acc += d0 * d0 + d1 * d1;
        }
    }

    // wave (64-lane) shuffle reduction
    #pragma unroll
    for (int off = 32; off > 0; off >>= 1)
        acc += __shfl_down(acc, off, 64);

    __shared__ float wsum[4];               // 256 threads = 4 waves
    const int lane = threadIdx.x & 63;
    const int w    = threadIdx.x >> 6;
    if (lane == 0) wsum[w] = acc;
    __syncthreads();
    if (threadIdx.x == 0) {
        // distinct slot per block: no same-address atomic contention
        partial[blockIdx.x] = (wsum[0] + wsum[1]) + (wsum[2] + wsum[3]);
    }
}

__global__ __launch_bounds__(256) void reduce_kernel(
    const float* __restrict__ partial,
    float* __restrict__ out) {

    const int tid = threadIdx.x;
    float acc = 0.0f;
    #pragma unroll
    for (int i = 0; i < NBLOCKS / 256; ++i)
        acc += partial[tid + 256 * i];

    #pragma unroll
    for (int off = 32; off > 0; off >>= 1)
        acc += __shfl_down(acc, off, 64);

    __shared__ float wsum[4];
    const int lane = tid & 63;
    const int w    = tid >> 6;
    if (lane == 0) wsum[w] = acc;
    __syncthreads();
    if (tid == 0)
        out[0] = ((wsum[0] + wsum[1]) + (wsum[2] + wsum[3])) * (1.0f / (float)ND);
}

extern "C" void kernel_launch(void* const* d_in, const int* in_sizes, int n_in,
                              void* d_out, int out_size, void* d_ws, size_t ws_size,
                              hipStream_t stream) {
    const float* para  = (const float*)d_in[0];   // (2,2)
    const float* omega = (const float*)d_in[1];   // (2M, 10)
    const float* infid = (const float*)d_in[2];   // (2M,)
    float* out     = (float*)d_out;
    float* partial = (float*)d_ws;                // 1024 * 4 B

    loss_kernel<<<NBLOCKS, BLK, 0, stream>>>(para, omega, infid, partial);
    reduce_kernel<<<1, 256, 0, stream>>>(partial, out);
}